// Round 4
// baseline (550.649 us; speedup 1.0000x reference)
//
#include <hip/hip_runtime.h>

constexpr int NN = 100000;
constexpr int NE = 1600000;
constexpr int SCAN_BLK = 1024;                        // elements per scan block
constexpr int NB = (NN + SCAN_BLK - 1) / SCAN_BLK;    // 98 scan blocks

// ---------------- fallback path (round-1 kernels, used only if ws too small) --

__global__ __launch_bounds__(256) void k_init(const float* __restrict__ x,
                                              const float* __restrict__ eps,
                                              float* __restrict__ out) {
    const float s = 1.0f + eps[0];
    const float4* x4 = (const float4*)x;
    float4* o4 = (float4*)out;
    const int total = NN * 16;
    for (int i = blockIdx.x * blockDim.x + threadIdx.x; i < total;
         i += gridDim.x * blockDim.x) {
        float4 v = x4[i];
        v.x *= s; v.y *= s; v.z *= s; v.w *= s;
        o4[i] = v;
    }
}

__global__ __launch_bounds__(256) void k_edges(const float* __restrict__ x,
                                               const int* __restrict__ ei,
                                               const float* __restrict__ ea,
                                               float* __restrict__ out) {
    const int* dst = ei;
    const int* src = ei + NE;
    const float4* ea4 = (const float4*)ea;
    const float4* x4 = (const float4*)x;
    const int total = NE * 16;
    for (int g = blockIdx.x * blockDim.x + threadIdx.x; g < total;
         g += gridDim.x * blockDim.x) {
        const int e = g >> 4;
        const int c = g & 15;
        const int s = src[e];
        const int d = dst[e];
        float4 a  = ea4[g];
        float4 xv = x4[s * 16 + c];
        float* base = out + d * 64 + c * 4;
        atomicAdd(base + 0, fmaxf(xv.x + a.x, 0.0f));
        atomicAdd(base + 1, fmaxf(xv.y + a.y, 0.0f));
        atomicAdd(base + 2, fmaxf(xv.z + a.z, 0.0f));
        atomicAdd(base + 3, fmaxf(xv.w + a.w, 0.0f));
    }
}

__global__ __launch_bounds__(256) void k_linear(const float* __restrict__ W,
                                                const float* __restrict__ bias,
                                                float* __restrict__ out) {
    __shared__ float Ws[64 * 64];
    __shared__ float bs[64];
    for (int i = threadIdx.x; i < 1024; i += blockDim.x)
        ((float4*)Ws)[i] = ((const float4*)W)[i];
    if (threadIdx.x < 16)
        ((float4*)bs)[threadIdx.x] = ((const float4*)bias)[threadIdx.x];
    __syncthreads();
    const int n = blockIdx.x * blockDim.x + threadIdx.x;
    if (n >= NN) return;
    float4* row = (float4*)(out + n * 64);
    float h[64];
#pragma unroll
    for (int k = 0; k < 16; ++k) {
        float4 v = row[k];
        h[4 * k + 0] = v.x; h[4 * k + 1] = v.y;
        h[4 * k + 2] = v.z; h[4 * k + 3] = v.w;
    }
#pragma unroll
    for (int jt = 0; jt < 4; ++jt) {
        float acc[16];
#pragma unroll
        for (int j = 0; j < 16; ++j) acc[j] = bs[jt * 16 + j];
#pragma unroll
        for (int d = 0; d < 64; ++d) {
            const float hd = h[d];
#pragma unroll
            for (int j = 0; j < 16; ++j)
                acc[j] = fmaf(hd, Ws[d * 64 + jt * 16 + j], acc[j]);
        }
#pragma unroll
        for (int j = 0; j < 4; ++j)
            row[jt * 4 + j] = make_float4(acc[4 * j + 0], acc[4 * j + 1],
                                          acc[4 * j + 2], acc[4 * j + 3]);
    }
}

// ---------------- sorted path --------------------------------------------------

__global__ __launch_bounds__(256) void k_zero(int* __restrict__ counts) {
    for (int i = blockIdx.x * blockDim.x + threadIdx.x; i < NN;
         i += gridDim.x * blockDim.x)
        counts[i] = 0;
}

// 4 edges per thread via int4 loads
__global__ __launch_bounds__(256) void k_hist(const int* __restrict__ dst,
                                              int* __restrict__ counts) {
    const int4* d4 = (const int4*)dst;
    const int total = NE / 4;
    for (int i = blockIdx.x * blockDim.x + threadIdx.x; i < total;
         i += gridDim.x * blockDim.x) {
        const int4 d = d4[i];
        atomicAdd(&counts[d.x], 1);
        atomicAdd(&counts[d.y], 1);
        atomicAdd(&counts[d.z], 1);
        atomicAdd(&counts[d.w], 1);
    }
}

__global__ __launch_bounds__(256) void k_scan_block(const int* __restrict__ counts,
                                                    int* __restrict__ offsets,
                                                    int* __restrict__ bsum) {
    __shared__ int sd[256];
    const int t = threadIdx.x;
    const int base = blockIdx.x * SCAN_BLK;
    int c[4];
    int s = 0;
#pragma unroll
    for (int k = 0; k < 4; ++k) {
        const int i = base + t * 4 + k;
        c[k] = (i < NN) ? counts[i] : 0;
        s += c[k];
    }
    sd[t] = s;
    __syncthreads();
#pragma unroll
    for (int off = 1; off < 256; off <<= 1) {
        int v = (t >= off) ? sd[t - off] : 0;
        __syncthreads();
        sd[t] += v;
        __syncthreads();
    }
    int excl = sd[t] - s;
#pragma unroll
    for (int k = 0; k < 4; ++k) {
        const int i = base + t * 4 + k;
        if (i < NN) offsets[i] = excl;
        excl += c[k];
    }
    if (t == 255) bsum[blockIdx.x] = sd[255];
}

__global__ __launch_bounds__(128) void k_scan_sums(const int* __restrict__ bsum,
                                                   int* __restrict__ bsum_ex) {
    __shared__ int sd[128];
    const int t = threadIdx.x;
    const int v = (t < NB) ? bsum[t] : 0;
    sd[t] = v;
    __syncthreads();
#pragma unroll
    for (int off = 1; off < 128; off <<= 1) {
        int u = (t >= off) ? sd[t - off] : 0;
        __syncthreads();
        sd[t] += u;
        __syncthreads();
    }
    bsum_ex[t] = sd[t] - v;
}

__global__ __launch_bounds__(256) void k_scan_add(int* __restrict__ offsets,
                                                  const int* __restrict__ bsum_ex,
                                                  int* __restrict__ cursor) {
    for (int i = blockIdx.x * blockDim.x + threadIdx.x; i < NN;
         i += gridDim.x * blockDim.x) {
        const int v = offsets[i] + bsum_ex[i >> 10];
        offsets[i] = v;
        cursor[i] = v;
    }
    if (blockIdx.x == 0 && threadIdx.x == 0) offsets[NN] = NE;
}

// scatter {edge_id, src_id} into dst-sorted order; 4 edges per thread
__global__ __launch_bounds__(256) void k_scatter(const int* __restrict__ dst,
                                                 const int* __restrict__ src,
                                                 int* __restrict__ cursor,
                                                 int2* __restrict__ ps) {
    const int4* d4 = (const int4*)dst;
    const int4* s4 = (const int4*)src;
    const int total = NE / 4;
    for (int i = blockIdx.x * blockDim.x + threadIdx.x; i < total;
         i += gridDim.x * blockDim.x) {
        const int4 d = d4[i];
        const int4 s = s4[i];
        const int e = i * 4;
        int p0 = atomicAdd(&cursor[d.x], 1);
        int p1 = atomicAdd(&cursor[d.y], 1);
        int p2 = atomicAdd(&cursor[d.z], 1);
        int p3 = atomicAdd(&cursor[d.w], 1);
        ps[p0] = make_int2(e + 0, s.x);
        ps[p1] = make_int2(e + 1, s.y);
        ps[p2] = make_int2(e + 2, s.z);
        ps[p3] = make_int2(e + 3, s.w);
    }
}

// Fused aggregate + self-term + linear.
// One NODE per 16-lane group (4 independent nodes per wave). Lane l16 owns
// dims [4*l16 .. 4*l16+3] of its node's row. Edge loop: 4-deep unroll ->
// 8 independent 256B row loads in flight per group (32/wave). Epilogue:
// linear within the group via __shfl(.,q,16) broadcast + float4 LDS W reads.
__global__ __launch_bounds__(256) void k_agg_lin(const float* __restrict__ x,
                                                 const float* __restrict__ ea,
                                                 const int* __restrict__ offsets,
                                                 const int2* __restrict__ ps,
                                                 const float* __restrict__ epsp,
                                                 const float* __restrict__ W,
                                                 const float* __restrict__ bias,
                                                 float* __restrict__ out) {
    __shared__ float Ws[64 * 64];
    __shared__ float bs[64];
    for (int i = threadIdx.x; i < 1024; i += 256)
        ((float4*)Ws)[i] = ((const float4*)W)[i];
    if (threadIdx.x < 16)
        ((float4*)bs)[threadIdx.x] = ((const float4*)bias)[threadIdx.x];
    __syncthreads();

    const float epsv = 1.0f + epsp[0];
    const int l16 = threadIdx.x & 15;
    const int grp_in_blk = threadIdx.x >> 4;          // 0..15
    const int ngroups = gridDim.x * 16;
    const float4* x4 = (const float4*)x;
    const float4* ea4 = (const float4*)ea;
    const float4* Ws4 = (const float4*)Ws;
    const float4* bs4 = (const float4*)bs;
    float4* out4 = (float4*)out;

    for (int n = blockIdx.x * 16 + grp_in_blk; n < NN; n += ngroups) {
        const int beg = offsets[n];
        const int end = offsets[n + 1];
        float4 acc = make_float4(0.f, 0.f, 0.f, 0.f);

        for (int j = beg; j < end; j += 4) {
            const bool v1 = (j + 1) < end;
            const bool v2 = (j + 2) < end;
            const bool v3 = (j + 3) < end;
            const int2 e0 = ps[j];
            const int2 e1 = ps[v1 ? j + 1 : j];
            const int2 e2 = ps[v2 ? j + 2 : j];
            const int2 e3 = ps[v3 ? j + 3 : j];
            const float4 A0 = ea4[e0.x * 16 + l16];
            const float4 X0 = x4[e0.y * 16 + l16];
            const float4 A1 = ea4[e1.x * 16 + l16];
            const float4 X1 = x4[e1.y * 16 + l16];
            const float4 A2 = ea4[e2.x * 16 + l16];
            const float4 X2 = x4[e2.y * 16 + l16];
            const float4 A3 = ea4[e3.x * 16 + l16];
            const float4 X3 = x4[e3.y * 16 + l16];
            acc.x += fmaxf(X0.x + A0.x, 0.f);
            acc.y += fmaxf(X0.y + A0.y, 0.f);
            acc.z += fmaxf(X0.z + A0.z, 0.f);
            acc.w += fmaxf(X0.w + A0.w, 0.f);
            if (v1) {
                acc.x += fmaxf(X1.x + A1.x, 0.f);
                acc.y += fmaxf(X1.y + A1.y, 0.f);
                acc.z += fmaxf(X1.z + A1.z, 0.f);
                acc.w += fmaxf(X1.w + A1.w, 0.f);
            }
            if (v2) {
                acc.x += fmaxf(X2.x + A2.x, 0.f);
                acc.y += fmaxf(X2.y + A2.y, 0.f);
                acc.z += fmaxf(X2.z + A2.z, 0.f);
                acc.w += fmaxf(X2.w + A2.w, 0.f);
            }
            if (v3) {
                acc.x += fmaxf(X3.x + A3.x, 0.f);
                acc.y += fmaxf(X3.y + A3.y, 0.f);
                acc.z += fmaxf(X3.z + A3.z, 0.f);
                acc.w += fmaxf(X3.w + A3.w, 0.f);
            }
        }

        // self term: h = x[n]*(1+eps) + agg
        const float4 xs = x4[n * 16 + l16];
        acc.x = fmaf(xs.x, epsv, acc.x);
        acc.y = fmaf(xs.y, epsv, acc.y);
        acc.z = fmaf(xs.z, epsv, acc.z);
        acc.w = fmaf(xs.w, epsv, acc.w);

        // linear within the 16-lane group: o[l16*4+k] = b + sum_d h[d]*W[d][..]
        float4 o = bs4[l16];
#pragma unroll
        for (int d = 0; d < 64; ++d) {
            const int q = d >> 2;
            const int r = d & 3;
            float hd;
            if (r == 0)      hd = __shfl(acc.x, q, 16);
            else if (r == 1) hd = __shfl(acc.y, q, 16);
            else if (r == 2) hd = __shfl(acc.z, q, 16);
            else             hd = __shfl(acc.w, q, 16);
            const float4 w = Ws4[d * 16 + l16];
            o.x = fmaf(hd, w.x, o.x);
            o.y = fmaf(hd, w.y, o.y);
            o.z = fmaf(hd, w.z, o.z);
            o.w = fmaf(hd, w.w, o.w);
        }
        out4[n * 16 + l16] = o;
    }
}

extern "C" void kernel_launch(void* const* d_in, const int* in_sizes, int n_in,
                              void* d_out, int out_size, void* d_ws, size_t ws_size,
                              hipStream_t stream) {
    const float* x   = (const float*)d_in[0];
    const int*   ei  = (const int*)d_in[1];
    const float* ea  = (const float*)d_in[2];
    const float* eps = (const float*)d_in[3];
    const float* W   = (const float*)d_in[4];
    const float* b   = (const float*)d_in[5];
    float* out = (float*)d_out;

    const int* dst = ei;        // edge_index[0]
    const int* src = ei + NE;   // edge_index[1]

    // workspace layout (ints); pad so ps is 8B-aligned
    int* counts  = (int*)d_ws;            // NN
    int* offsets = counts + NN;           // NN + 1
    int* cursor  = offsets + NN + 1;      // NN
    int* bsum    = cursor + NN;           // 128
    int* bsum_ex = bsum + 128;            // 128
    int2* ps     = (int2*)(bsum_ex + 128 + 1);  // NE pairs (+1 pad -> 8B aligned)
    const size_t ws_needed = (size_t)(NN * 3 + 2 + 256 + 2 * NE) * sizeof(int);

    if (ws_size < ws_needed) {            // insurance: round-1 atomic path
        k_init<<<2048, 256, 0, stream>>>(x, eps, out);
        k_edges<<<2048, 256, 0, stream>>>(x, ei, ea, out);
        k_linear<<<(NN + 255) / 256, 256, 0, stream>>>(W, b, out);
        return;
    }

    k_zero<<<128, 256, 0, stream>>>(counts);
    k_hist<<<1024, 256, 0, stream>>>(dst, counts);
    k_scan_block<<<NB, 256, 0, stream>>>(counts, offsets, bsum);
    k_scan_sums<<<1, 128, 0, stream>>>(bsum, bsum_ex);
    k_scan_add<<<256, 256, 0, stream>>>(offsets, bsum_ex, cursor);
    k_scatter<<<1024, 256, 0, stream>>>(dst, src, cursor, ps);
    k_agg_lin<<<2048, 256, 0, stream>>>(x, ea, offsets, ps, eps, W, b, out);
}

// Round 5
// 396.637 us; speedup vs baseline: 1.3883x; 1.3883x over previous
//
#include <hip/hip_runtime.h>

constexpr int NN = 100000;
constexpr int NE = 1600000;
constexpr int SCAN_BLK = 1024;
constexpr int NB = (NN + SCAN_BLK - 1) / SCAN_BLK;    // 98 scan blocks
constexpr int CHUNK = 64;                             // edges per 16-lane group
constexpr int NGRP = NE / CHUNK;                      // 25000 (exact)

// ---------------- fallback path (round-1 kernels, used only if ws too small) --

__global__ __launch_bounds__(256) void k_edges(const float* __restrict__ x,
                                               const int* __restrict__ ei,
                                               const float* __restrict__ ea,
                                               float* __restrict__ out) {
    const int* dst = ei;
    const int* src = ei + NE;
    const float4* ea4 = (const float4*)ea;
    const float4* x4 = (const float4*)x;
    const int total = NE * 16;
    for (int g = blockIdx.x * blockDim.x + threadIdx.x; g < total;
         g += gridDim.x * blockDim.x) {
        const int e = g >> 4;
        const int c = g & 15;
        const int s = src[e];
        const int d = dst[e];
        float4 a  = ea4[g];
        float4 xv = x4[s * 16 + c];
        float* base = out + d * 64 + c * 4;
        atomicAdd(base + 0, fmaxf(xv.x + a.x, 0.0f));
        atomicAdd(base + 1, fmaxf(xv.y + a.y, 0.0f));
        atomicAdd(base + 2, fmaxf(xv.z + a.z, 0.0f));
        atomicAdd(base + 3, fmaxf(xv.w + a.w, 0.0f));
    }
}

// ---------------- main path ----------------------------------------------------

// out[n] = x[n] * (1+eps)   (base for atomic flushes; overwritten for interior)
__global__ __launch_bounds__(256) void k_init(const float* __restrict__ x,
                                              const float* __restrict__ eps,
                                              float* __restrict__ out) {
    const float s = 1.0f + eps[0];
    const float4* x4 = (const float4*)x;
    float4* o4 = (float4*)out;
    const int total = NN * 16;
    for (int i = blockIdx.x * blockDim.x + threadIdx.x; i < total;
         i += gridDim.x * blockDim.x) {
        float4 v = x4[i];
        v.x *= s; v.y *= s; v.z *= s; v.w *= s;
        o4[i] = v;
    }
}

__global__ __launch_bounds__(256) void k_zero(int* __restrict__ counts) {
    for (int i = blockIdx.x * blockDim.x + threadIdx.x; i < NN;
         i += gridDim.x * blockDim.x)
        counts[i] = 0;
}

__global__ __launch_bounds__(256) void k_hist(const int* __restrict__ dst,
                                              int* __restrict__ counts) {
    const int4* d4 = (const int4*)dst;
    const int total = NE / 4;
    for (int i = blockIdx.x * blockDim.x + threadIdx.x; i < total;
         i += gridDim.x * blockDim.x) {
        const int4 d = d4[i];
        atomicAdd(&counts[d.x], 1);
        atomicAdd(&counts[d.y], 1);
        atomicAdd(&counts[d.z], 1);
        atomicAdd(&counts[d.w], 1);
    }
}

__global__ __launch_bounds__(256) void k_scan_block(const int* __restrict__ counts,
                                                    int* __restrict__ offsets,
                                                    int* __restrict__ bsum) {
    __shared__ int sd[256];
    const int t = threadIdx.x;
    const int base = blockIdx.x * SCAN_BLK;
    int c[4];
    int s = 0;
#pragma unroll
    for (int k = 0; k < 4; ++k) {
        const int i = base + t * 4 + k;
        c[k] = (i < NN) ? counts[i] : 0;
        s += c[k];
    }
    sd[t] = s;
    __syncthreads();
#pragma unroll
    for (int off = 1; off < 256; off <<= 1) {
        int v = (t >= off) ? sd[t - off] : 0;
        __syncthreads();
        sd[t] += v;
        __syncthreads();
    }
    int excl = sd[t] - s;
#pragma unroll
    for (int k = 0; k < 4; ++k) {
        const int i = base + t * 4 + k;
        if (i < NN) offsets[i] = excl;
        excl += c[k];
    }
    if (t == 255) bsum[blockIdx.x] = sd[255];
}

__global__ __launch_bounds__(128) void k_scan_sums(const int* __restrict__ bsum,
                                                   int* __restrict__ bsum_ex) {
    __shared__ int sd[128];
    const int t = threadIdx.x;
    const int v = (t < NB) ? bsum[t] : 0;
    sd[t] = v;
    __syncthreads();
#pragma unroll
    for (int off = 1; off < 128; off <<= 1) {
        int u = (t >= off) ? sd[t - off] : 0;
        __syncthreads();
        sd[t] += u;
        __syncthreads();
    }
    bsum_ex[t] = sd[t] - v;
}

__global__ __launch_bounds__(256) void k_scan_add(int* __restrict__ offsets,
                                                  const int* __restrict__ bsum_ex,
                                                  int* __restrict__ cursor) {
    for (int i = blockIdx.x * blockDim.x + threadIdx.x; i < NN;
         i += gridDim.x * blockDim.x) {
        const int v = offsets[i] + bsum_ex[i >> 10];
        offsets[i] = v;
        cursor[i] = v;
    }
    if (blockIdx.x == 0 && threadIdx.x == 0) offsets[NN] = NE;
}

// scatter {edge, src, dst, 0} into dst-sorted order; 4 edges per thread
__global__ __launch_bounds__(256) void k_scatter4(const int* __restrict__ dst,
                                                  const int* __restrict__ src,
                                                  int* __restrict__ cursor,
                                                  int4* __restrict__ ps) {
    const int4* d4 = (const int4*)dst;
    const int4* s4 = (const int4*)src;
    const int total = NE / 4;
    for (int i = blockIdx.x * blockDim.x + threadIdx.x; i < total;
         i += gridDim.x * blockDim.x) {
        const int4 d = d4[i];
        const int4 s = s4[i];
        const int e = i * 4;
        int p0 = atomicAdd(&cursor[d.x], 1);
        int p1 = atomicAdd(&cursor[d.y], 1);
        int p2 = atomicAdd(&cursor[d.z], 1);
        int p3 = atomicAdd(&cursor[d.w], 1);
        ps[p0] = make_int4(e + 0, s.x, d.x, 0);
        ps[p1] = make_int4(e + 1, s.y, d.y, 0);
        ps[p2] = make_int4(e + 2, s.z, d.z, 0);
        ps[p3] = make_int4(e + 3, s.w, d.w, 0);
    }
}

// Chunked walk over the dst-sorted edge stream.
// Each 16-lane group owns CHUNK consecutive sorted positions (lane = 4 dims).
// dst is non-decreasing across positions. Segment fully inside the chunk ->
// plain store of x[n]*(1+eps)+acc. Segment touching a chunk boundary ->
// atomicAdd onto the k_init base. Fixed trip count, streaming loads.
__global__ __launch_bounds__(256) void k_agg_chunk(const float* __restrict__ x,
                                                   const float* __restrict__ ea,
                                                   const int4* __restrict__ ps,
                                                   const float* __restrict__ epsp,
                                                   float* __restrict__ out) {
    const int gid = (blockIdx.x * blockDim.x + threadIdx.x) >> 4;
    if (gid >= NGRP) return;
    const int l16 = threadIdx.x & 15;
    const int begin = gid * CHUNK;
    const float epsv = 1.0f + epsp[0];
    const float4* x4 = (const float4*)x;
    const float4* ea4 = (const float4*)ea;
    float4* out4 = (float4*)out;

    const int prev_dst = (begin == 0) ? -1 : ps[begin - 1].z;

    float4 acc = make_float4(0.f, 0.f, 0.f, 0.f);
    int cur_dst = -2;
    bool open = false;   // acc continues a segment begun in the previous chunk

#pragma unroll 4
    for (int p = begin; p < begin + CHUNK; ++p) {
        const int4 t = ps[p];
        if (t.z != cur_dst) {
            if (cur_dst >= 0) {
                if (open) {
                    float* o = out + cur_dst * 64 + l16 * 4;
                    atomicAdd(o + 0, acc.x);
                    atomicAdd(o + 1, acc.y);
                    atomicAdd(o + 2, acc.z);
                    atomicAdd(o + 3, acc.w);
                } else {
                    const float4 xs = x4[cur_dst * 16 + l16];
                    float4 r;
                    r.x = fmaf(xs.x, epsv, acc.x);
                    r.y = fmaf(xs.y, epsv, acc.y);
                    r.z = fmaf(xs.z, epsv, acc.z);
                    r.w = fmaf(xs.w, epsv, acc.w);
                    out4[cur_dst * 16 + l16] = r;
                }
            }
            acc = make_float4(0.f, 0.f, 0.f, 0.f);
            open = (t.z == prev_dst);   // only possible for the first segment
            cur_dst = t.z;
        }
        const float4 A = ea4[t.x * 16 + l16];
        const float4 X = x4[t.y * 16 + l16];
        acc.x += fmaxf(X.x + A.x, 0.f);
        acc.y += fmaxf(X.y + A.y, 0.f);
        acc.z += fmaxf(X.z + A.z, 0.f);
        acc.w += fmaxf(X.w + A.w, 0.f);
    }

    // final flush: partial if it began before the chunk or continues after it
    const bool cont = (begin + CHUNK < NE) && (ps[begin + CHUNK].z == cur_dst);
    if (open || cont) {
        float* o = out + cur_dst * 64 + l16 * 4;
        atomicAdd(o + 0, acc.x);
        atomicAdd(o + 1, acc.y);
        atomicAdd(o + 2, acc.z);
        atomicAdd(o + 3, acc.w);
    } else {
        const float4 xs = x4[cur_dst * 16 + l16];
        float4 r;
        r.x = fmaf(xs.x, epsv, acc.x);
        r.y = fmaf(xs.y, epsv, acc.y);
        r.z = fmaf(xs.z, epsv, acc.z);
        r.w = fmaf(xs.w, epsv, acc.w);
        out4[cur_dst * 16 + l16] = r;
    }
}

// In-place linear, one node per 16-lane group (NN*16 threads, 6250 blocks).
__global__ __launch_bounds__(256) void k_linear2(const float* __restrict__ W,
                                                 const float* __restrict__ bias,
                                                 float* __restrict__ out) {
    __shared__ float Ws[64 * 64];
    __shared__ float bs[64];
    for (int i = threadIdx.x; i < 1024; i += 256)
        ((float4*)Ws)[i] = ((const float4*)W)[i];
    if (threadIdx.x < 16)
        ((float4*)bs)[threadIdx.x] = ((const float4*)bias)[threadIdx.x];
    __syncthreads();

    const int l16 = threadIdx.x & 15;
    const int gid = (blockIdx.x * 256 + threadIdx.x) >> 4;   // node id, < NN exact
    const float4* Ws4 = (const float4*)Ws;
    float4* out4 = (float4*)out;

    const float4 h4 = out4[gid * 16 + l16];   // this lane's 4 dims of h
    float4 o = ((const float4*)bs)[l16];
#pragma unroll
    for (int d = 0; d < 64; ++d) {
        const int q = d >> 2;
        const int r = d & 3;
        float hd;
        if (r == 0)      hd = __shfl(h4.x, q, 16);
        else if (r == 1) hd = __shfl(h4.y, q, 16);
        else if (r == 2) hd = __shfl(h4.z, q, 16);
        else             hd = __shfl(h4.w, q, 16);
        const float4 w = Ws4[d * 16 + l16];
        o.x = fmaf(hd, w.x, o.x);
        o.y = fmaf(hd, w.y, o.y);
        o.z = fmaf(hd, w.z, o.z);
        o.w = fmaf(hd, w.w, o.w);
    }
    out4[gid * 16 + l16] = o;
}

extern "C" void kernel_launch(void* const* d_in, const int* in_sizes, int n_in,
                              void* d_out, int out_size, void* d_ws, size_t ws_size,
                              hipStream_t stream) {
    const float* x   = (const float*)d_in[0];
    const int*   ei  = (const int*)d_in[1];
    const float* ea  = (const float*)d_in[2];
    const float* eps = (const float*)d_in[3];
    const float* W   = (const float*)d_in[4];
    const float* b   = (const float*)d_in[5];
    float* out = (float*)d_out;

    const int* dst = ei;        // edge_index[0]
    const int* src = ei + NE;   // edge_index[1]

    // workspace layout: ps first (16B aligned at base)
    int4* ps     = (int4*)d_ws;           // NE
    int* counts  = (int*)(ps + NE);       // NN
    int* offsets = counts + NN;           // NN + 1
    int* cursor  = offsets + NN + 1;      // NN
    int* bsum    = cursor + NN;           // 128
    int* bsum_ex = bsum + 128;            // 128
    const size_t ws_needed = (size_t)(4 * NE + 3 * NN + 1 + 256) * sizeof(int);

    if (ws_size < ws_needed) {            // insurance: atomic fallback
        k_init<<<2048, 256, 0, stream>>>(x, eps, out);
        k_edges<<<2048, 256, 0, stream>>>(x, ei, ea, out);
        k_linear2<<<NN * 16 / 256, 256, 0, stream>>>(W, b, out);
        return;
    }

    k_zero<<<128, 256, 0, stream>>>(counts);
    k_hist<<<1024, 256, 0, stream>>>(dst, counts);
    k_scan_block<<<NB, 256, 0, stream>>>(counts, offsets, bsum);
    k_scan_sums<<<1, 128, 0, stream>>>(bsum, bsum_ex);
    k_scan_add<<<256, 256, 0, stream>>>(offsets, bsum_ex, cursor);
    k_scatter4<<<1024, 256, 0, stream>>>(dst, src, cursor, ps);
    k_init<<<2048, 256, 0, stream>>>(x, eps, out);
    k_agg_chunk<<<(NGRP * 16 + 255) / 256, 256, 0, stream>>>(x, ea, ps, eps, out);
    k_linear2<<<NN * 16 / 256, 256, 0, stream>>>(W, b, out);
}

// Round 6
// 393.995 us; speedup vs baseline: 1.3976x; 1.0067x over previous
//
#include <hip/hip_runtime.h>

constexpr int NN = 100000;
constexpr int NE = 1600000;
constexpr int SCAN_BLK = 1024;
constexpr int NB = (NN + SCAN_BLK - 1) / SCAN_BLK;    // 98 scan blocks
constexpr int CHUNK = 64;                             // edges per 16-lane group
constexpr int NGRP = NE / CHUNK;                      // 25000 (exact)

// ---------------- fallback path (used only if ws too small) -------------------

__global__ __launch_bounds__(256) void k_edges(const float* __restrict__ x,
                                               const int* __restrict__ ei,
                                               const float* __restrict__ ea,
                                               float* __restrict__ out) {
    const int* dst = ei;
    const int* src = ei + NE;
    const float4* ea4 = (const float4*)ea;
    const float4* x4 = (const float4*)x;
    const int total = NE * 16;
    for (int g = blockIdx.x * blockDim.x + threadIdx.x; g < total;
         g += gridDim.x * blockDim.x) {
        const int e = g >> 4;
        const int c = g & 15;
        const int s = src[e];
        const int d = dst[e];
        float4 a  = ea4[g];
        float4 xv = x4[s * 16 + c];
        float* base = out + d * 64 + c * 4;
        atomicAdd(base + 0, fmaxf(xv.x + a.x, 0.0f));
        atomicAdd(base + 1, fmaxf(xv.y + a.y, 0.0f));
        atomicAdd(base + 2, fmaxf(xv.z + a.z, 0.0f));
        atomicAdd(base + 3, fmaxf(xv.w + a.w, 0.0f));
    }
}

// ---------------- main path ----------------------------------------------------

// out[n] = x[n] * (1+eps)   (base for atomic flushes; overwritten for interior)
__global__ __launch_bounds__(256) void k_init(const float* __restrict__ x,
                                              const float* __restrict__ eps,
                                              float* __restrict__ out) {
    const float s = 1.0f + eps[0];
    const float4* x4 = (const float4*)x;
    float4* o4 = (float4*)out;
    const int total = NN * 16;
    for (int i = blockIdx.x * blockDim.x + threadIdx.x; i < total;
         i += gridDim.x * blockDim.x) {
        float4 v = x4[i];
        v.x *= s; v.y *= s; v.z *= s; v.w *= s;
        o4[i] = v;
    }
}

__global__ __launch_bounds__(256) void k_zero(int* __restrict__ counts) {
    for (int i = blockIdx.x * blockDim.x + threadIdx.x; i < NN;
         i += gridDim.x * blockDim.x)
        counts[i] = 0;
}

__global__ __launch_bounds__(256) void k_hist(const int* __restrict__ dst,
                                              int* __restrict__ counts) {
    const int4* d4 = (const int4*)dst;
    const int total = NE / 4;
    for (int i = blockIdx.x * blockDim.x + threadIdx.x; i < total;
         i += gridDim.x * blockDim.x) {
        const int4 d = d4[i];
        atomicAdd(&counts[d.x], 1);
        atomicAdd(&counts[d.y], 1);
        atomicAdd(&counts[d.z], 1);
        atomicAdd(&counts[d.w], 1);
    }
}

__global__ __launch_bounds__(256) void k_scan_block(const int* __restrict__ counts,
                                                    int* __restrict__ offsets,
                                                    int* __restrict__ bsum) {
    __shared__ int sd[256];
    const int t = threadIdx.x;
    const int base = blockIdx.x * SCAN_BLK;
    int c[4];
    int s = 0;
#pragma unroll
    for (int k = 0; k < 4; ++k) {
        const int i = base + t * 4 + k;
        c[k] = (i < NN) ? counts[i] : 0;
        s += c[k];
    }
    sd[t] = s;
    __syncthreads();
#pragma unroll
    for (int off = 1; off < 256; off <<= 1) {
        int v = (t >= off) ? sd[t - off] : 0;
        __syncthreads();
        sd[t] += v;
        __syncthreads();
    }
    int excl = sd[t] - s;
#pragma unroll
    for (int k = 0; k < 4; ++k) {
        const int i = base + t * 4 + k;
        if (i < NN) offsets[i] = excl;
        excl += c[k];
    }
    if (t == 255) bsum[blockIdx.x] = sd[255];
}

__global__ __launch_bounds__(128) void k_scan_sums(const int* __restrict__ bsum,
                                                   int* __restrict__ bsum_ex) {
    __shared__ int sd[128];
    const int t = threadIdx.x;
    const int v = (t < NB) ? bsum[t] : 0;
    sd[t] = v;
    __syncthreads();
#pragma unroll
    for (int off = 1; off < 128; off <<= 1) {
        int u = (t >= off) ? sd[t - off] : 0;
        __syncthreads();
        sd[t] += u;
        __syncthreads();
    }
    bsum_ex[t] = sd[t] - v;
}

__global__ __launch_bounds__(256) void k_scan_add(int* __restrict__ offsets,
                                                  const int* __restrict__ bsum_ex,
                                                  int* __restrict__ cursor) {
    for (int i = blockIdx.x * blockDim.x + threadIdx.x; i < NN;
         i += gridDim.x * blockDim.x) {
        const int v = offsets[i] + bsum_ex[i >> 10];
        offsets[i] = v;
        cursor[i] = v;
    }
    if (blockIdx.x == 0 && threadIdx.x == 0) offsets[NN] = NE;
}

// scatter {edge, src, dst, 0} into dst-sorted order; 4 edges per thread
__global__ __launch_bounds__(256) void k_scatter4(const int* __restrict__ dst,
                                                  const int* __restrict__ src,
                                                  int* __restrict__ cursor,
                                                  int4* __restrict__ ps) {
    const int4* d4 = (const int4*)dst;
    const int4* s4 = (const int4*)src;
    const int total = NE / 4;
    for (int i = blockIdx.x * blockDim.x + threadIdx.x; i < total;
         i += gridDim.x * blockDim.x) {
        const int4 d = d4[i];
        const int4 s = s4[i];
        const int e = i * 4;
        int p0 = atomicAdd(&cursor[d.x], 1);
        int p1 = atomicAdd(&cursor[d.y], 1);
        int p2 = atomicAdd(&cursor[d.z], 1);
        int p3 = atomicAdd(&cursor[d.w], 1);
        ps[p0] = make_int4(e + 0, s.x, d.x, 0);
        ps[p1] = make_int4(e + 1, s.y, d.y, 0);
        ps[p2] = make_int4(e + 2, s.z, d.z, 0);
        ps[p3] = make_int4(e + 3, s.w, d.w, 0);
    }
}

__device__ __forceinline__ void flush_seg(float* __restrict__ out,
                                          const float4* __restrict__ x4,
                                          int node, int l16, bool partial,
                                          float epsv, const float4& acc) {
    if (partial) {
        float* o = out + node * 64 + l16 * 4;
        atomicAdd(o + 0, acc.x);
        atomicAdd(o + 1, acc.y);
        atomicAdd(o + 2, acc.z);
        atomicAdd(o + 3, acc.w);
    } else {
        const float4 xs = x4[node * 16 + l16];
        float4 r;
        r.x = fmaf(xs.x, epsv, acc.x);
        r.y = fmaf(xs.y, epsv, acc.y);
        r.z = fmaf(xs.z, epsv, acc.z);
        r.w = fmaf(xs.w, epsv, acc.w);
        ((float4*)out)[node * 16 + l16] = r;
    }
}

// Chunked walk over the dst-sorted edge stream.
// Batch structure: one coalesced 256B load brings 16 descriptors per group;
// __shfl broadcasts decouple row-load addresses from the descriptor stream,
// so ~16 independent 256B row loads are in flight per group.
__global__ __launch_bounds__(256, 4) void k_agg_chunk(const float* __restrict__ x,
                                                      const float* __restrict__ ea,
                                                      const int4* __restrict__ ps,
                                                      const float* __restrict__ epsp,
                                                      float* __restrict__ out) {
    const int gid = (blockIdx.x * blockDim.x + threadIdx.x) >> 4;
    if (gid >= NGRP) return;
    const int l16 = threadIdx.x & 15;
    const int begin = gid * CHUNK;
    const float epsv = 1.0f + epsp[0];
    const float4* x4 = (const float4*)x;
    const float4* ea4 = (const float4*)ea;

    const int prev_dst = (begin == 0) ? -1 : ps[begin - 1].z;

    float4 acc = make_float4(0.f, 0.f, 0.f, 0.f);
    int cur_dst = -2;
    bool open = false;   // acc continues a segment begun in the previous chunk

    for (int b = 0; b < CHUNK / 16; ++b) {
        const int4 myt = ps[begin + b * 16 + l16];   // coalesced descriptor batch
#pragma unroll 8
        for (int k = 0; k < 16; ++k) {
            const int eid = __shfl(myt.x, k, 16);
            const int sid = __shfl(myt.y, k, 16);
            const int did = __shfl(myt.z, k, 16);
            if (did != cur_dst) {
                if (cur_dst >= 0)
                    flush_seg(out, x4, cur_dst, l16, open, epsv, acc);
                acc = make_float4(0.f, 0.f, 0.f, 0.f);
                open = (did == prev_dst);   // only the first segment can continue
                cur_dst = did;
            }
            const float4 A = ea4[eid * 16 + l16];
            const float4 X = x4[sid * 16 + l16];
            acc.x += fmaxf(X.x + A.x, 0.f);
            acc.y += fmaxf(X.y + A.y, 0.f);
            acc.z += fmaxf(X.z + A.z, 0.f);
            acc.w += fmaxf(X.w + A.w, 0.f);
        }
    }

    // final flush: partial if it began before the chunk or continues after it
    const bool cont = (begin + CHUNK < NE) && (ps[begin + CHUNK].z == cur_dst);
    flush_seg(out, x4, cur_dst, l16, open || cont, epsv, acc);
}

// In-place linear, one node per 16-lane group (NN*16 threads, 6250 blocks).
__global__ __launch_bounds__(256) void k_linear2(const float* __restrict__ W,
                                                 const float* __restrict__ bias,
                                                 float* __restrict__ out) {
    __shared__ float Ws[64 * 64];
    __shared__ float bs[64];
    for (int i = threadIdx.x; i < 1024; i += 256)
        ((float4*)Ws)[i] = ((const float4*)W)[i];
    if (threadIdx.x < 16)
        ((float4*)bs)[threadIdx.x] = ((const float4*)bias)[threadIdx.x];
    __syncthreads();

    const int l16 = threadIdx.x & 15;
    const int gid = (blockIdx.x * 256 + threadIdx.x) >> 4;   // node id, < NN exact
    const float4* Ws4 = (const float4*)Ws;
    float4* out4 = (float4*)out;

    const float4 h4 = out4[gid * 16 + l16];   // this lane's 4 dims of h
    float4 o = ((const float4*)bs)[l16];
#pragma unroll
    for (int d = 0; d < 64; ++d) {
        const int q = d >> 2;
        const int r = d & 3;
        float hd;
        if (r == 0)      hd = __shfl(h4.x, q, 16);
        else if (r == 1) hd = __shfl(h4.y, q, 16);
        else if (r == 2) hd = __shfl(h4.z, q, 16);
        else             hd = __shfl(h4.w, q, 16);
        const float4 w = Ws4[d * 16 + l16];
        o.x = fmaf(hd, w.x, o.x);
        o.y = fmaf(hd, w.y, o.y);
        o.z = fmaf(hd, w.z, o.z);
        o.w = fmaf(hd, w.w, o.w);
    }
    out4[gid * 16 + l16] = o;
}

extern "C" void kernel_launch(void* const* d_in, const int* in_sizes, int n_in,
                              void* d_out, int out_size, void* d_ws, size_t ws_size,
                              hipStream_t stream) {
    const float* x   = (const float*)d_in[0];
    const int*   ei  = (const int*)d_in[1];
    const float* ea  = (const float*)d_in[2];
    const float* eps = (const float*)d_in[3];
    const float* W   = (const float*)d_in[4];
    const float* b   = (const float*)d_in[5];
    float* out = (float*)d_out;

    const int* dst = ei;        // edge_index[0]
    const int* src = ei + NE;   // edge_index[1]

    // workspace layout: ps first (16B aligned at base)
    int4* ps     = (int4*)d_ws;           // NE
    int* counts  = (int*)(ps + NE);       // NN
    int* offsets = counts + NN;           // NN + 1
    int* cursor  = offsets + NN + 1;      // NN
    int* bsum    = cursor + NN;           // 128
    int* bsum_ex = bsum + 128;            // 128
    const size_t ws_needed = (size_t)(4 * NE + 3 * NN + 1 + 256) * sizeof(int);

    if (ws_size < ws_needed) {            // insurance: atomic fallback
        k_init<<<2048, 256, 0, stream>>>(x, eps, out);
        k_edges<<<2048, 256, 0, stream>>>(x, ei, ea, out);
        k_linear2<<<NN * 16 / 256, 256, 0, stream>>>(W, b, out);
        return;
    }

    k_zero<<<128, 256, 0, stream>>>(counts);
    k_hist<<<1024, 256, 0, stream>>>(dst, counts);
    k_scan_block<<<NB, 256, 0, stream>>>(counts, offsets, bsum);
    k_scan_sums<<<1, 128, 0, stream>>>(bsum, bsum_ex);
    k_scan_add<<<256, 256, 0, stream>>>(offsets, bsum_ex, cursor);
    k_scatter4<<<1024, 256, 0, stream>>>(dst, src, cursor, ps);
    k_init<<<2048, 256, 0, stream>>>(x, eps, out);
    k_agg_chunk<<<(NGRP * 16 + 255) / 256, 256, 0, stream>>>(x, ea, ps, eps, out);
    k_linear2<<<NN * 16 / 256, 256, 0, stream>>>(W, b, out);
}

// Round 7
// 374.954 us; speedup vs baseline: 1.4686x; 1.0508x over previous
//
#include <hip/hip_runtime.h>

typedef float f4 __attribute__((ext_vector_type(4)));

constexpr int NN = 100000;
constexpr int NE = 1600000;
constexpr int SCAN_BLK = 1024;
constexpr int NB = (NN + SCAN_BLK - 1) / SCAN_BLK;    // 98 scan blocks

__device__ __forceinline__ f4 relu_add(f4 a, f4 b) {
    f4 s = a + b;
    s.x = fmaxf(s.x, 0.f);
    s.y = fmaxf(s.y, 0.f);
    s.z = fmaxf(s.z, 0.f);
    s.w = fmaxf(s.w, 0.f);
    return s;
}

// ---------------- fallback path (used only if ws too small) -------------------

__global__ __launch_bounds__(256) void k_init(const float* __restrict__ x,
                                              const float* __restrict__ eps,
                                              float* __restrict__ out) {
    const float s = 1.0f + eps[0];
    const float4* x4 = (const float4*)x;
    float4* o4 = (float4*)out;
    const int total = NN * 16;
    for (int i = blockIdx.x * blockDim.x + threadIdx.x; i < total;
         i += gridDim.x * blockDim.x) {
        float4 v = x4[i];
        v.x *= s; v.y *= s; v.z *= s; v.w *= s;
        o4[i] = v;
    }
}

__global__ __launch_bounds__(256) void k_edges(const float* __restrict__ x,
                                               const int* __restrict__ ei,
                                               const float* __restrict__ ea,
                                               float* __restrict__ out) {
    const int* dst = ei;
    const int* src = ei + NE;
    const float4* ea4 = (const float4*)ea;
    const float4* x4 = (const float4*)x;
    const int total = NE * 16;
    for (int g = blockIdx.x * blockDim.x + threadIdx.x; g < total;
         g += gridDim.x * blockDim.x) {
        const int e = g >> 4;
        const int c = g & 15;
        const int s = src[e];
        const int d = dst[e];
        float4 a  = ea4[g];
        float4 xv = x4[s * 16 + c];
        float* base = out + d * 64 + c * 4;
        atomicAdd(base + 0, fmaxf(xv.x + a.x, 0.0f));
        atomicAdd(base + 1, fmaxf(xv.y + a.y, 0.0f));
        atomicAdd(base + 2, fmaxf(xv.z + a.z, 0.0f));
        atomicAdd(base + 3, fmaxf(xv.w + a.w, 0.0f));
    }
}

// ---------------- main path ----------------------------------------------------

__global__ __launch_bounds__(256) void k_hist(const int* __restrict__ dst,
                                              int* __restrict__ counts) {
    const int4* d4 = (const int4*)dst;
    const int total = NE / 4;
    for (int i = blockIdx.x * blockDim.x + threadIdx.x; i < total;
         i += gridDim.x * blockDim.x) {
        const int4 d = d4[i];
        atomicAdd(&counts[d.x], 1);
        atomicAdd(&counts[d.y], 1);
        atomicAdd(&counts[d.z], 1);
        atomicAdd(&counts[d.w], 1);
    }
}

__global__ __launch_bounds__(256) void k_scan_block(const int* __restrict__ counts,
                                                    int* __restrict__ offsets,
                                                    int* __restrict__ bsum) {
    __shared__ int sd[256];
    const int t = threadIdx.x;
    const int base = blockIdx.x * SCAN_BLK;
    int c[4];
    int s = 0;
#pragma unroll
    for (int k = 0; k < 4; ++k) {
        const int i = base + t * 4 + k;
        c[k] = (i < NN) ? counts[i] : 0;
        s += c[k];
    }
    sd[t] = s;
    __syncthreads();
#pragma unroll
    for (int off = 1; off < 256; off <<= 1) {
        int v = (t >= off) ? sd[t - off] : 0;
        __syncthreads();
        sd[t] += v;
        __syncthreads();
    }
    int excl = sd[t] - s;
#pragma unroll
    for (int k = 0; k < 4; ++k) {
        const int i = base + t * 4 + k;
        if (i < NN) offsets[i] = excl;
        excl += c[k];
    }
    if (t == 255) bsum[blockIdx.x] = sd[255];
}

__global__ __launch_bounds__(128) void k_scan_sums(const int* __restrict__ bsum,
                                                   int* __restrict__ bsum_ex) {
    __shared__ int sd[128];
    const int t = threadIdx.x;
    const int v = (t < NB) ? bsum[t] : 0;
    sd[t] = v;
    __syncthreads();
#pragma unroll
    for (int off = 1; off < 128; off <<= 1) {
        int u = (t >= off) ? sd[t - off] : 0;
        __syncthreads();
        sd[t] += u;
        __syncthreads();
    }
    bsum_ex[t] = sd[t] - v;
}

__global__ __launch_bounds__(256) void k_scan_add(int* __restrict__ offsets,
                                                  const int* __restrict__ bsum_ex,
                                                  int* __restrict__ cursor) {
    for (int i = blockIdx.x * blockDim.x + threadIdx.x; i < NN;
         i += gridDim.x * blockDim.x) {
        const int v = offsets[i] + bsum_ex[i >> 10];
        offsets[i] = v;
        cursor[i] = v;
    }
    if (blockIdx.x == 0 && threadIdx.x == 0) offsets[NN] = NE;
}

// scatter {edge, src} into dst-sorted order; 4 edges per thread
__global__ __launch_bounds__(256) void k_scatter(const int* __restrict__ dst,
                                                 const int* __restrict__ src,
                                                 int* __restrict__ cursor,
                                                 int2* __restrict__ ps) {
    const int4* d4 = (const int4*)dst;
    const int4* s4 = (const int4*)src;
    const int total = NE / 4;
    for (int i = blockIdx.x * blockDim.x + threadIdx.x; i < total;
         i += gridDim.x * blockDim.x) {
        const int4 d = d4[i];
        const int4 s = s4[i];
        const int e = i * 4;
        int p0 = atomicAdd(&cursor[d.x], 1);
        int p1 = atomicAdd(&cursor[d.y], 1);
        int p2 = atomicAdd(&cursor[d.z], 1);
        int p3 = atomicAdd(&cursor[d.w], 1);
        ps[p0] = make_int2(e + 0, s.x);
        ps[p1] = make_int2(e + 1, s.y);
        ps[p2] = make_int2(e + 2, s.z);
        ps[p3] = make_int2(e + 3, s.w);
    }
}

// Per-node aggregation: one node per 16-lane group, offsets-driven segments,
// zero float atomics, single plain store. Inner body is a BRANCHLESS unroll-4:
// 4 descriptor loads then 8 independent row loads with no branches/stores
// between them, so the compiler can keep 8 gathers in flight per group.
__global__ __launch_bounds__(256) void k_agg(const float* __restrict__ x,
                                             const float* __restrict__ ea,
                                             const int* __restrict__ offsets,
                                             const int2* __restrict__ ps,
                                             const float* __restrict__ epsp,
                                             float* __restrict__ out) {
    const int l16 = threadIdx.x & 15;
    const int gid = (blockIdx.x * blockDim.x + threadIdx.x) >> 4;
    if (gid >= NN) return;
    const int n = gid;                       // exactly one node per group
    const float epsv = 1.0f + epsp[0];
    const f4* x4 = (const f4*)x;
    const f4* ea4 = (const f4*)ea;
    f4* out4 = (f4*)out;

    const int beg = offsets[n];
    const int end = offsets[n + 1];
    f4 acc = {0.f, 0.f, 0.f, 0.f};

    int j = beg;
    for (; j + 4 <= end; j += 4) {
        const int2 d0 = ps[j];
        const int2 d1 = ps[j + 1];
        const int2 d2 = ps[j + 2];
        const int2 d3 = ps[j + 3];
        const f4 A0 = ea4[d0.x * 16 + l16];
        const f4 X0 = x4[d0.y * 16 + l16];
        const f4 A1 = ea4[d1.x * 16 + l16];
        const f4 X1 = x4[d1.y * 16 + l16];
        const f4 A2 = ea4[d2.x * 16 + l16];
        const f4 X2 = x4[d2.y * 16 + l16];
        const f4 A3 = ea4[d3.x * 16 + l16];
        const f4 X3 = x4[d3.y * 16 + l16];
        acc += relu_add(X0, A0);
        acc += relu_add(X1, A1);
        acc += relu_add(X2, A2);
        acc += relu_add(X3, A3);
    }
    for (; j < end; ++j) {                   // tail (0..3 edges; also deg<4)
        const int2 d = ps[j];
        acc += relu_add(x4[d.y * 16 + l16], ea4[d.x * 16 + l16]);
    }

    const f4 xs = x4[n * 16 + l16];
    f4 r;
    r.x = fmaf(xs.x, epsv, acc.x);
    r.y = fmaf(xs.y, epsv, acc.y);
    r.z = fmaf(xs.z, epsv, acc.z);
    r.w = fmaf(xs.w, epsv, acc.w);
    out4[n * 16 + l16] = r;
}

// In-place linear, one node per 16-lane group (NN*16 threads, 6250 blocks).
__global__ __launch_bounds__(256) void k_linear2(const float* __restrict__ W,
                                                 const float* __restrict__ bias,
                                                 float* __restrict__ out) {
    __shared__ float Ws[64 * 64];
    __shared__ float bs[64];
    for (int i = threadIdx.x; i < 1024; i += 256)
        ((float4*)Ws)[i] = ((const float4*)W)[i];
    if (threadIdx.x < 16)
        ((float4*)bs)[threadIdx.x] = ((const float4*)bias)[threadIdx.x];
    __syncthreads();

    const int l16 = threadIdx.x & 15;
    const int gid = (blockIdx.x * 256 + threadIdx.x) >> 4;   // node id, < NN exact
    const float4* Ws4 = (const float4*)Ws;
    float4* out4 = (float4*)out;

    const float4 h4 = out4[gid * 16 + l16];   // this lane's 4 dims of h
    float4 o = ((const float4*)bs)[l16];
#pragma unroll
    for (int d = 0; d < 64; ++d) {
        const int q = d >> 2;
        const int r = d & 3;
        float hd;
        if (r == 0)      hd = __shfl(h4.x, q, 16);
        else if (r == 1) hd = __shfl(h4.y, q, 16);
        else if (r == 2) hd = __shfl(h4.z, q, 16);
        else             hd = __shfl(h4.w, q, 16);
        const float4 w = Ws4[d * 16 + l16];
        o.x = fmaf(hd, w.x, o.x);
        o.y = fmaf(hd, w.y, o.y);
        o.z = fmaf(hd, w.z, o.z);
        o.w = fmaf(hd, w.w, o.w);
    }
    out4[gid * 16 + l16] = o;
}

extern "C" void kernel_launch(void* const* d_in, const int* in_sizes, int n_in,
                              void* d_out, int out_size, void* d_ws, size_t ws_size,
                              hipStream_t stream) {
    const float* x   = (const float*)d_in[0];
    const int*   ei  = (const int*)d_in[1];
    const float* ea  = (const float*)d_in[2];
    const float* eps = (const float*)d_in[3];
    const float* W   = (const float*)d_in[4];
    const float* b   = (const float*)d_in[5];
    float* out = (float*)d_out;

    const int* dst = ei;        // edge_index[0]
    const int* src = ei + NE;   // edge_index[1]

    // workspace layout: ps first (8B aligned at base)
    int2* ps     = (int2*)d_ws;           // NE
    int* counts  = (int*)(ps + NE);       // NN
    int* offsets = counts + NN;           // NN + 1
    int* cursor  = offsets + NN + 1;      // NN
    int* bsum    = cursor + NN;           // 128
    int* bsum_ex = bsum + 128;            // 128
    const size_t ws_needed = (size_t)(2 * NE + 3 * NN + 1 + 256) * sizeof(int);

    if (ws_size < ws_needed) {            // insurance: atomic fallback
        k_init<<<2048, 256, 0, stream>>>(x, eps, out);
        k_edges<<<2048, 256, 0, stream>>>(x, ei, ea, out);
        k_linear2<<<NN * 16 / 256, 256, 0, stream>>>(W, b, out);
        return;
    }

    hipMemsetAsync(counts, 0, (size_t)NN * sizeof(int), stream);
    k_hist<<<1024, 256, 0, stream>>>(dst, counts);
    k_scan_block<<<NB, 256, 0, stream>>>(counts, offsets, bsum);
    k_scan_sums<<<1, 128, 0, stream>>>(bsum, bsum_ex);
    k_scan_add<<<256, 256, 0, stream>>>(offsets, bsum_ex, cursor);
    k_scatter<<<1024, 256, 0, stream>>>(dst, src, cursor, ps);
    k_agg<<<(NN * 16 + 255) / 256, 256, 0, stream>>>(x, ea, offsets, ps, eps, out);
    k_linear2<<<NN * 16 / 256, 256, 0, stream>>>(W, b, out);
}